// Round 5
// baseline (190.810 us; speedup 1.0000x reference)
//
#include <hip/hip_runtime.h>
#include <stdint.h>

// Problem constants (B, L, DIM) = (2, 2048, 1024); H=16, DH=64, W=256.
#define B_    2
#define L_    2048
#define DIM_  1024
#define H_    16
#define DH_   64
#define WWIN  256

typedef __attribute__((ext_vector_type(4))) float f32x4;
typedef __attribute__((ext_vector_type(8))) short bf16x8;

__device__ __forceinline__ unsigned short f2bf(float x) {
  union { float f; unsigned u; } c; c.f = x;
  unsigned r = c.u + 0x7fffu + ((c.u >> 16) & 1u);   // RNE
  return (unsigned short)(r >> 16);
}

// ---------------------------------------------------------------- cast fp32->bf16
struct CastArgs {
  const float* src[7];
  unsigned short* dst[7];
  int n[7];
};
__global__ __launch_bounds__(256) void cast_bf16_kernel(CastArgs a) {
  int arr = blockIdx.y;
  int i = (blockIdx.x * 256 + threadIdx.x) * 4;
  if (i >= a.n[arr]) return;
  float4 v = *(const float4*)(a.src[arr] + i);
  ushort4 o;
  o.x = f2bf(v.x); o.y = f2bf(v.y); o.z = f2bf(v.z); o.w = f2bf(v.w);
  *(ushort4*)(a.dst[arr] + i) = o;
}

// ---------------------------------------------------------------- GEMM C = A @ B^T
// A: (M,1024) bf16 row-major, Bt: (N,1024) bf16 row-major (K-contiguous both).
// Tile 128x64 (BM x BN), BK=64; 4 waves each own a 32x64 strip.
// R4 counters: fetch fixed (27 MB) but dur unchanged -> barrier/vmcnt(0)-drain
// bound (MfmaUtil 25%). R5: single-barrier ping-pong LDS double-buffer; loads
// for k+1 are issued into the alternate buffer BEFORE the MFMA phase of k, so
// the compiler's vmcnt(0)-before-s_barrier drains loads that already had a
// full compute phase in flight. One barrier per K-iter. LDS 48 KB.
#define BM 128
#define BN 64
#define BK 64

__device__ __forceinline__ void gld_lds16(const void* g, void* l) {
  __builtin_amdgcn_global_load_lds(
      (const __attribute__((address_space(1))) void*)g,
      (__attribute__((address_space(3))) void*)l, 16, 0, 0);
}

// As: 2 x 8192 shorts, Bs: 2 x 4096 shorts (ping-pong).
__device__ __forceinline__ void gemm_core_1024(
    const unsigned short* __restrict__ A, const unsigned short* __restrict__ Bt,
    unsigned short* As, unsigned short* Bs, f32x4 (&acc)[2][4],
    int m0, int n0) {
  const int tid = threadIdx.x;
  const int wave = tid >> 6, lane = tid & 63;
  const int quad = lane >> 4, l16 = lane & 15;
  const int srow = tid >> 3, sc = tid & 7;

  // stage K-tile k0 into buffer buf
  auto stage = [&](int k0, int buf) {
    unsigned short* Ad = As + buf * 8192;
    unsigned short* Bd = Bs + buf * 4096;
    #pragma unroll
    for (int rd = 0; rd < 4; ++rd) {       // A: 128 rows x 8 chunks
      int row = rd * 32 + srow;
      int cs = sc ^ (row & 7);             // swizzled global chunk -> linear LDS slot
      gld_lds16(A + (size_t)(m0 + row) * 1024 + k0 + cs * 8, Ad + row * BK + sc * 8);
    }
    #pragma unroll
    for (int rd = 0; rd < 2; ++rd) {       // B: 64 rows x 8 chunks
      int row = rd * 32 + srow;
      int cs = sc ^ (row & 7);
      gld_lds16(Bt + (size_t)(n0 + row) * 1024 + k0 + cs * 8, Bd + row * BK + sc * 8);
    }
  };

  stage(0, 0);
  for (int k = 0; k < 16; ++k) {
    const int cur = k & 1;
    __syncthreads();                       // drains vmcnt -> buf[cur] ready; also
                                           // orders last iter's readers of buf[cur^1]
    if (k < 15) stage((k + 1) * BK, cur ^ 1);
    const unsigned short* Ac = As + cur * 8192;
    const unsigned short* Bc = Bs + cur * 4096;
    #pragma unroll
    for (int ks = 0; ks < 2; ++ks) {
      bf16x8 af[2], bfr[4];
      #pragma unroll
      for (int i = 0; i < 2; ++i) {
        int row = wave * 32 + i * 16 + l16;
        int ch = (ks * 4 + quad) ^ (row & 7);
        af[i] = *(const bf16x8*)(Ac + row * BK + ch * 8);
      }
      #pragma unroll
      for (int j = 0; j < 4; ++j) {
        int row = j * 16 + l16;
        int ch = (ks * 4 + quad) ^ (row & 7);
        bfr[j] = *(const bf16x8*)(Bc + row * BK + ch * 8);
      }
      #pragma unroll
      for (int i = 0; i < 2; ++i)
        #pragma unroll
        for (int j = 0; j < 4; ++j)
          acc[i][j] = __builtin_amdgcn_mfma_f32_16x16x32_bf16(af[i], bfr[j], acc[i][j], 0, 0, 0);
    }
  }
}

// Projection GEMM with fused epilogues:
//   z in {0,1}: q/k projection + RoPE (pair partner d^1 in adjacent lane ->
//               __shfl_xor(.,1); HW sin/cos in revolutions), scatter to (B,H,L,DH).
//   z == 2   : v projection + per-wave 64x32 LDS transpose (stride-36 pad),
//              (B,H,DH,L) store.
// Flat grid of 1536; XCD-aware decode: each XCD gets 12 (m,z)-groups x 16 n.
struct ProjArgs {
  const unsigned short* A[3];
  const unsigned short* Bt[3];
  unsigned short* C[3];
};
__global__ __launch_bounds__(256) void gemm_proj_kernel(ProjArgs pa) {
  __shared__ unsigned short SH[24576];   // As dbuf (16384) + Bs dbuf (8192) = 48 KB
  unsigned short* As = SH;
  unsigned short* Bs = SH + 16384;

  // XCD-aware decode: xcd = b&7 (dispatch heuristic), 16 same-(m,z) n-blocks per XCD
  const int bflat = blockIdx.x;
  const int xcd = bflat & 7, s = bflat >> 3;      // s: 0..191
  const int nblk = s & 15;                        // n strip (also the head h)
  const int mz = xcd * 12 + (s >> 4);             // 0..95
  const int z = mz >> 5;                          // input select
  const int mblk = mz & 31;
  const int m0 = mblk * BM, n0 = nblk * BN;

  f32x4 acc[2][4] = {};
  gemm_core_1024(pa.A[z], pa.Bt[z], As, Bs, acc, m0, n0);

  const int tid = threadIdx.x;
  const int lane = tid & 63, wave = tid >> 6;
  const int quad = lane >> 4, l16 = lane & 15;

  if (z < 2) {
    // -------- RoPE + scatter to (B,H,L,DH); h = nblk is block-uniform --------
    float frev[4];
    #pragma unroll
    for (int j = 0; j < 4; ++j) {
      int d = j * 16 + l16;
      // freq/(2pi) = 10000^(-(d/2)/32) / (2pi)
      frev[j] = exp2f(-(float)(d >> 1) * 0.41524101186092029f) * 0.15915494309189535f;
    }
    unsigned short* C = pa.C[z];
    const int h = nblk;
    const bool even = (l16 & 1) == 0;
    #pragma unroll
    for (int i = 0; i < 2; ++i)
      #pragma unroll
      for (int r = 0; r < 4; ++r) {
        int m = m0 + wave * 32 + i * 16 + quad * 4 + r;
        int b = m >> 11, l = m & (L_ - 1);
        float lf = (float)l;
        #pragma unroll
        for (int j = 0; j < 4; ++j) {
          int d = j * 16 + l16;
          float v = acc[i][j][r];
          float p = __shfl_xor(v, 1);       // partner at d^1
          float a = lf * frev[j];
          float t = a - floorf(a);          // revolutions in [0,1)
          float sn = __builtin_amdgcn_sinf(t);
          float cs = __builtin_amdgcn_cosf(t);
          float o = even ? (v * cs - p * sn) : (p * sn + v * cs);
          C[(((size_t)b * H_ + h) * L_ + l) * DH_ + d] = f2bf(o);
        }
      }
  } else {
    // -------- V: per-wave 64(n) x 32(m) transpose via LDS, store (B,H,DH,L) --------
    __syncthreads();   // T overlaps dbuf regions other waves may still be reading
    unsigned short* T = SH + wave * 2304;   // 64 rows x 36 shorts (pad: 72B stride)
    #pragma unroll
    for (int i = 0; i < 2; ++i)
      #pragma unroll
      for (int j = 0; j < 4; ++j) {
        int nw = j * 16 + l16;
        int hm = i * 4 + quad;                      // 4-short group in m (0..7)
        uint2 pk;
        pk.x = (unsigned)f2bf(acc[i][j][0]) | ((unsigned)f2bf(acc[i][j][1]) << 16);
        pk.y = (unsigned)f2bf(acc[i][j][2]) | ((unsigned)f2bf(acc[i][j][3]) << 16);
        *(uint2*)(T + nw * 36 + hm * 4) = pk;       // ds_write_b64
      }
    asm volatile("s_waitcnt lgkmcnt(0)" ::: "memory");  // wave-private: no barrier
    int h = nblk;                                   // BN=64: one head per block
    int d = lane;
    int b = m0 >> 11;
    int lbase = (m0 & (L_ - 1)) + wave * 32;
    unsigned short* C = pa.C[2];
    size_t rowbase = (((size_t)b * H_ + h) * DH_ + d) * L_ + lbase;
    #pragma unroll
    for (int t = 0; t < 4; ++t) {
      uint2 lo = *(uint2*)(T + lane * 36 + t * 8);
      uint2 hi = *(uint2*)(T + lane * 36 + t * 8 + 4);
      uint4 o = {lo.x, lo.y, hi.x, hi.y};           // m-local [8t, 8t+8)
      *(uint4*)(C + rowbase + t * 8) = o;
    }
  }
}

// Output GEMM: fp32 row-major epilogue straight to d_out.
// Flat grid of 512; XCD-aware decode: each XCD gets 4 m-groups x 16 n.
__global__ __launch_bounds__(256) void gemm_out_kernel(
    const unsigned short* __restrict__ A, const unsigned short* __restrict__ Bt,
    float* __restrict__ C) {
  __shared__ unsigned short SH[24576];
  unsigned short* As = SH;
  unsigned short* Bs = SH + 16384;

  const int bflat = blockIdx.x;
  const int xcd = bflat & 7, s = bflat >> 3;      // s: 0..63
  const int nblk = s & 15;
  const int mblk = xcd * 4 + (s >> 4);            // 0..31
  const int m0 = mblk * BM, n0 = nblk * BN;

  f32x4 acc[2][4] = {};
  gemm_core_1024(A, Bt, As, Bs, acc, m0, n0);

  const int lane = threadIdx.x & 63, wave = threadIdx.x >> 6;
  const int quad = lane >> 4, l16 = lane & 15;
  #pragma unroll
  for (int i = 0; i < 2; ++i)
    #pragma unroll
    for (int j = 0; j < 4; ++j)
      #pragma unroll
      for (int r = 0; r < 4; ++r) {
        int m = m0 + wave * 32 + i * 16 + quad * 4 + r;
        int n = n0 + j * 16 + l16;
        C[(size_t)m * DIM_ + n] = acc[i][j][r];
      }
}

// ---------------------------------------------------------------- attention
// One block per (64-query tile, bh). Window = [q0-256, q0+63] -> 320 keys = 20 chunks.
// Wave w owns queries qb..qb+15; S kept in 20 f32x4 accumulators (80 VGPRs).
// K and V_t staged in halves of 160 keys into one 23KB LDS buffer; P goes through a
// small per-wave LDS buffer to convert C-layout -> A-fragment layout (m120 pattern).
// Flat grid of 1024; XCD-aware decode: each XCD owns 4 bh x 32 q-tiles (KV fits L2).
#define NCH 20
__global__ __launch_bounds__(256) void attn_kernel(
    const unsigned short* __restrict__ Qh,  // (B,H,L,DH) roped
    const unsigned short* __restrict__ Kh,  // (B,H,L,DH) roped
    const unsigned short* __restrict__ Vt,  // (B,H,DH,L)
    unsigned short* __restrict__ O) {       // (B,L,H*DH) bf16
  __shared__ unsigned short KVs[160 * 72];  // 23040 B; V half uses 64*168 = 21504 B
  __shared__ unsigned short Ps[4][16 * 40]; // per-wave P chunk (16 q x 32 k, stride 40)
  const int tid = threadIdx.x;
  const int wave = tid >> 6, lane = tid & 63;
  const int quad = lane >> 4, l16 = lane & 15;

  const int bflat = blockIdx.x;
  const int xcd = bflat & 7, s = bflat >> 3;  // s: 0..127
  const int qt = s >> 2;                      // 0..31 q-tile
  const int bh = xcd * 4 + (s & 3);           // 0..31

  const int q0 = qt * 64;
  const int kwin0 = q0 - WWIN;
  const int qb = q0 + wave * 16;

  // Q fragments held in registers: A[m=lane&15][k=quad*8+j], k0 in {0,32}
  bf16x8 qf0, qf1;
  {
    const unsigned short* qrow = Qh + ((size_t)bh * L_ + qb + l16) * DH_;
    qf0 = *(const bf16x8*)(qrow + quad * 8);
    qf1 = *(const bf16x8*)(qrow + 32 + quad * 8);
  }

  f32x4 S[NCH] = {};

  // ---- S = Q K^T over two K halves ----
  #pragma unroll
  for (int half = 0; half < 2; ++half) {
    __syncthreads();
    for (int rep = 0; rep < 5; ++rep) {       // stage 160 rows x 8 chunks
      int ci = rep * 256 + tid;
      int row = ci >> 3, c = ci & 7;
      int key = kwin0 + half * 160 + row;
      uint4 val = {0, 0, 0, 0};
      if (key >= 0)
        val = *(const uint4*)(Kh + ((size_t)bh * L_ + key) * DH_ + c * 8);
      *(uint4*)(&KVs[row * 72 + c * 8]) = val;  // stride 72: 2-way banks (free)
    }
    __syncthreads();
    #pragma unroll
    for (int cc = 0; cc < 10; ++cc) {
      const unsigned short* kr = &KVs[(cc * 16 + l16) * 72];
      bf16x8 kf0 = *(const bf16x8*)(kr + quad * 8);
      bf16x8 kf1 = *(const bf16x8*)(kr + 32 + quad * 8);
      int c = half * 10 + cc;
      S[c] = __builtin_amdgcn_mfma_f32_16x16x32_bf16(qf0, kf0, S[c], 0, 0, 0);
      S[c] = __builtin_amdgcn_mfma_f32_16x16x32_bf16(qf1, kf1, S[c], 0, 0, 0);
    }
  }

  // ---- masked softmax in registers (rows live in one 16-lane quad) ----
  float inv_l[4];
  #pragma unroll
  for (int r = 0; r < 4; ++r) {
    int i = qb + quad * 4 + r;
    float mx = -1e30f;
    #pragma unroll
    for (int c = 0; c < NCH; ++c) {
      int key = kwin0 + c * 16 + l16;
      bool valid = (key >= 0) && (key <= i) && (key >= i - WWIN);
      float v = valid ? S[c][r] * 0.125f : -1e30f;  // DH^-0.5 = 1/8; garbage masked out
      S[c][r] = v;
      mx = fmaxf(mx, v);
    }
    mx = fmaxf(mx, __shfl_xor(mx, 1));
    mx = fmaxf(mx, __shfl_xor(mx, 2));
    mx = fmaxf(mx, __shfl_xor(mx, 4));
    mx = fmaxf(mx, __shfl_xor(mx, 8));
    float sum = 0.f;
    #pragma unroll
    for (int c = 0; c < NCH; ++c) {
      float e = __expf(S[c][r] - mx);
      S[c][r] = e;
      sum += e;
    }
    sum += __shfl_xor(sum, 1);
    sum += __shfl_xor(sum, 2);
    sum += __shfl_xor(sum, 4);
    sum += __shfl_xor(sum, 8);
    inv_l[r] = 1.0f / sum;
  }

  // ---- O = P V over two V halves ----
  f32x4 Oacc[4] = {};
  #pragma unroll
  for (int half = 0; half < 2; ++half) {
    __syncthreads();
    for (int rep = 0; rep < 5; ++rep) {       // stage V_t: 64 dh-rows x 20 chunks
      int ci = rep * 256 + tid;
      int row = ci / 20, c = ci % 20;
      int key0 = kwin0 + half * 160 + c * 8;
      uint4 val = {0, 0, 0, 0};
      if (key0 >= 0)
        val = *(const uint4*)(Vt + ((size_t)bh * DH_ + row) * L_ + key0);
      *(uint4*)(&KVs[row * 168 + c * 8]) = val;  // stride 168: 2-way banks (free)
    }
    __syncthreads();
    #pragma unroll
    for (int s5 = 0; s5 < 5; ++s5) {
      int cbase = half * 10 + s5 * 2;
      unsigned short* pw = &Ps[wave][0];
      #pragma unroll
      for (int cc = 0; cc < 2; ++cc)
        #pragma unroll
        for (int r = 0; r < 4; ++r) {
          float p = S[cbase + cc][r] * inv_l[r];
          pw[(quad * 4 + r) * 40 + cc * 16 + l16] = f2bf(p);  // C-layout -> [m][k]
        }
      asm volatile("s_waitcnt lgkmcnt(0)" ::: "memory");  // wave-private buffer: no barrier
      bf16x8 pf = *(const bf16x8*)(pw + l16 * 40 + quad * 8);  // A-frag read
      int lk = s5 * 32 + quad * 8;
      #pragma unroll
      for (int t = 0; t < 4; ++t) {
        bf16x8 vf = *(const bf16x8*)(&KVs[(t * 16 + l16) * 168 + lk]);
        Oacc[t] = __builtin_amdgcn_mfma_f32_16x16x32_bf16(pf, vf, Oacc[t], 0, 0, 0);
      }
    }
  }

  // epilogue: (B, L, H*DH) bf16
  int b = bh >> 4, h = bh & 15;
  #pragma unroll
  for (int t = 0; t < 4; ++t)
    #pragma unroll
    for (int r = 0; r < 4; ++r) {
      int l = qb + quad * 4 + r;
      int col = h * DH_ + t * 16 + l16;
      O[((size_t)b * L_ + l) * (H_ * DH_) + col] = f2bf(Oacc[t][r]);
    }
}

// ---------------------------------------------------------------- launch
extern "C" void kernel_launch(void* const* d_in, const int* in_sizes, int n_in,
                              void* d_out, int out_size, void* d_ws, size_t ws_size,
                              hipStream_t stream) {
  const float* q  = (const float*)d_in[0];
  const float* k  = (const float*)d_in[1];
  const float* v  = (const float*)d_in[2];
  const float* wq = (const float*)d_in[3];
  const float* wk = (const float*)d_in[4];
  const float* wv = (const float*)d_in[5];
  const float* wo = (const float*)d_in[6];

  const size_t SA = (size_t)B_ * L_ * DIM_;  // 4,194,304
  const size_t SW = (size_t)DIM_ * DIM_;     // 1,048,576
  unsigned short* w   = (unsigned short*)d_ws;
  unsigned short* qb  = w; w += SA;
  unsigned short* kb  = w; w += SA;
  unsigned short* vb  = w; w += SA;
  unsigned short* wqb = w; w += SW;
  unsigned short* wkb = w; w += SW;
  unsigned short* wvb = w; w += SW;
  unsigned short* wob = w; w += SW;
  unsigned short* qh  = w; w += SA;   // (B,H,L,DH) roped
  unsigned short* kh  = w; w += SA;   // (B,H,L,DH) roped
  unsigned short* vt  = w; w += SA;   // (B,H,DH,L)
  unsigned short* Ob  = w; w += SA;   // (B,L,H*DH)

  CastArgs ca;
  ca.src[0] = q;  ca.dst[0] = qb;  ca.n[0] = (int)SA;
  ca.src[1] = k;  ca.dst[1] = kb;  ca.n[1] = (int)SA;
  ca.src[2] = v;  ca.dst[2] = vb;  ca.n[2] = (int)SA;
  ca.src[3] = wq; ca.dst[3] = wqb; ca.n[3] = (int)SW;
  ca.src[4] = wk; ca.dst[4] = wkb; ca.n[4] = (int)SW;
  ca.src[5] = wv; ca.dst[5] = wvb; ca.n[5] = (int)SW;
  ca.src[6] = wo; ca.dst[6] = wob; ca.n[6] = (int)SW;
  cast_bf16_kernel<<<dim3(SA / (256 * 4), 7), 256, 0, stream>>>(ca);

  ProjArgs pa;
  pa.A[0] = qb; pa.Bt[0] = wqb; pa.C[0] = qh;
  pa.A[1] = kb; pa.Bt[1] = wkb; pa.C[1] = kh;
  pa.A[2] = vb; pa.Bt[2] = wvb; pa.C[2] = vt;
  gemm_proj_kernel<<<dim3(16 * 32 * 3), 256, 0, stream>>>(pa);

  attn_kernel<<<dim3(32 * 32), 256, 0, stream>>>(qh, kh, vt, Ob);
  gemm_out_kernel<<<dim3(16 * 32), 256, 0, stream>>>(Ob, wob, (float*)d_out);
}

// Round 6
// 184.143 us; speedup vs baseline: 1.0362x; 1.0362x over previous
//
#include <hip/hip_runtime.h>
#include <stdint.h>

// Problem constants (B, L, DIM) = (2, 2048, 1024); H=16, DH=64, W=256.
#define B_    2
#define L_    2048
#define DIM_  1024
#define H_    16
#define DH_   64
#define WWIN  256

typedef __attribute__((ext_vector_type(4))) float f32x4;
typedef __attribute__((ext_vector_type(8))) short bf16x8;

__device__ __forceinline__ unsigned short f2bf(float x) {
  union { float f; unsigned u; } c; c.f = x;
  unsigned r = c.u + 0x7fffu + ((c.u >> 16) & 1u);   // RNE
  return (unsigned short)(r >> 16);
}

// ---------------------------------------------------------------- cast fp32->bf16
struct CastArgs {
  const float* src[7];
  unsigned short* dst[7];
  int n[7];
};
__global__ __launch_bounds__(256) void cast_bf16_kernel(CastArgs a) {
  int arr = blockIdx.y;
  int i = (blockIdx.x * 256 + threadIdx.x) * 4;
  if (i >= a.n[arr]) return;
  float4 v = *(const float4*)(a.src[arr] + i);
  ushort4 o;
  o.x = f2bf(v.x); o.y = f2bf(v.y); o.z = f2bf(v.z); o.w = f2bf(v.w);
  *(ushort4*)(a.dst[arr] + i) = o;
}

// ---------------------------------------------------------------- GEMM C = A @ B^T
// Tile 128x64 (BM x BN), BK=64; single-barrier ping-pong LDS double buffer
// (R5): loads for k+1 are issued into the alternate buffer before the MFMA
// phase of k. XOR chunk swizzle breaks the 16-way conflict of 128B rows.
#define BM 128
#define BN 64
#define BK 64

__device__ __forceinline__ void gld_lds16(const void* g, void* l) {
  __builtin_amdgcn_global_load_lds(
      (const __attribute__((address_space(1))) void*)g,
      (__attribute__((address_space(3))) void*)l, 16, 0, 0);
}

// As: 2 x 8192 shorts, Bs: 2 x 4096 shorts (ping-pong).
__device__ __forceinline__ void gemm_core_1024(
    const unsigned short* __restrict__ A, const unsigned short* __restrict__ Bt,
    unsigned short* As, unsigned short* Bs, f32x4 (&acc)[2][4],
    int m0, int n0) {
  const int tid = threadIdx.x;
  const int wave = tid >> 6, lane = tid & 63;
  const int quad = lane >> 4, l16 = lane & 15;
  const int srow = tid >> 3, sc = tid & 7;

  auto stage = [&](int k0, int buf) {
    unsigned short* Ad = As + buf * 8192;
    unsigned short* Bd = Bs + buf * 4096;
    #pragma unroll
    for (int rd = 0; rd < 4; ++rd) {       // A: 128 rows x 8 chunks
      int row = rd * 32 + srow;
      int cs = sc ^ (row & 7);             // swizzled global chunk -> linear LDS slot
      gld_lds16(A + (size_t)(m0 + row) * 1024 + k0 + cs * 8, Ad + row * BK + sc * 8);
    }
    #pragma unroll
    for (int rd = 0; rd < 2; ++rd) {       // B: 64 rows x 8 chunks
      int row = rd * 32 + srow;
      int cs = sc ^ (row & 7);
      gld_lds16(Bt + (size_t)(n0 + row) * 1024 + k0 + cs * 8, Bd + row * BK + sc * 8);
    }
  };

  stage(0, 0);
  for (int k = 0; k < 16; ++k) {
    const int cur = k & 1;
    __syncthreads();                       // drains vmcnt -> buf[cur] ready; also
                                           // orders last iter's readers of buf[cur^1]
    if (k < 15) stage((k + 1) * BK, cur ^ 1);
    const unsigned short* Ac = As + cur * 8192;
    const unsigned short* Bc = Bs + cur * 4096;
    #pragma unroll
    for (int ks = 0; ks < 2; ++ks) {
      bf16x8 af[2], bfr[4];
      #pragma unroll
      for (int i = 0; i < 2; ++i) {
        int row = wave * 32 + i * 16 + l16;
        int ch = (ks * 4 + quad) ^ (row & 7);
        af[i] = *(const bf16x8*)(Ac + row * BK + ch * 8);
      }
      #pragma unroll
      for (int j = 0; j < 4; ++j) {
        int row = j * 16 + l16;
        int ch = (ks * 4 + quad) ^ (row & 7);
        bfr[j] = *(const bf16x8*)(Bc + row * BK + ch * 8);
      }
      #pragma unroll
      for (int i = 0; i < 2; ++i)
        #pragma unroll
        for (int j = 0; j < 4; ++j)
          acc[i][j] = __builtin_amdgcn_mfma_f32_16x16x32_bf16(af[i], bfr[j], acc[i][j], 0, 0, 0);
    }
  }
}

// Projection GEMM with fused epilogues (RoPE for q/k, V-transpose for v).
// Flat grid of 1536; XCD-aware decode: each XCD gets 12 (m,z)-groups x 16 n.
struct ProjArgs {
  const unsigned short* A[3];
  const unsigned short* Bt[3];
  unsigned short* C[3];
};
__global__ __launch_bounds__(256) void gemm_proj_kernel(ProjArgs pa) {
  __shared__ unsigned short SH[24576];   // As dbuf (16384) + Bs dbuf (8192) = 48 KB
  unsigned short* As = SH;
  unsigned short* Bs = SH + 16384;

  const int bflat = blockIdx.x;
  const int xcd = bflat & 7, s = bflat >> 3;      // s: 0..191
  const int nblk = s & 15;                        // n strip (also the head h)
  const int mz = xcd * 12 + (s >> 4);             // 0..95
  const int z = mz >> 5;                          // input select
  const int mblk = mz & 31;
  const int m0 = mblk * BM, n0 = nblk * BN;

  f32x4 acc[2][4] = {};
  gemm_core_1024(pa.A[z], pa.Bt[z], As, Bs, acc, m0, n0);

  const int tid = threadIdx.x;
  const int lane = tid & 63, wave = tid >> 6;
  const int quad = lane >> 4, l16 = lane & 15;

  if (z < 2) {
    // -------- RoPE + scatter to (B,H,L,DH); h = nblk is block-uniform --------
    float frev[4];
    #pragma unroll
    for (int j = 0; j < 4; ++j) {
      int d = j * 16 + l16;
      frev[j] = exp2f(-(float)(d >> 1) * 0.41524101186092029f) * 0.15915494309189535f;
    }
    unsigned short* C = pa.C[z];
    const int h = nblk;
    const bool even = (l16 & 1) == 0;
    #pragma unroll
    for (int i = 0; i < 2; ++i)
      #pragma unroll
      for (int r = 0; r < 4; ++r) {
        int m = m0 + wave * 32 + i * 16 + quad * 4 + r;
        int b = m >> 11, l = m & (L_ - 1);
        float lf = (float)l;
        #pragma unroll
        for (int j = 0; j < 4; ++j) {
          int d = j * 16 + l16;
          float v = acc[i][j][r];
          float p = __shfl_xor(v, 1);       // partner at d^1
          float a = lf * frev[j];
          float t = a - floorf(a);          // revolutions in [0,1)
          float sn = __builtin_amdgcn_sinf(t);
          float cs = __builtin_amdgcn_cosf(t);
          float o = even ? (v * cs - p * sn) : (p * sn + v * cs);
          C[(((size_t)b * H_ + h) * L_ + l) * DH_ + d] = f2bf(o);
        }
      }
  } else {
    // -------- V: per-wave 64(n) x 32(m) transpose via LDS, store (B,H,DH,L) --------
    __syncthreads();   // T overlaps dbuf regions other waves may still be reading
    unsigned short* T = SH + wave * 2304;   // 64 rows x 36 shorts (pad: 72B stride)
    #pragma unroll
    for (int i = 0; i < 2; ++i)
      #pragma unroll
      for (int j = 0; j < 4; ++j) {
        int nw = j * 16 + l16;
        int hm = i * 4 + quad;                      // 4-short group in m (0..7)
        uint2 pk;
        pk.x = (unsigned)f2bf(acc[i][j][0]) | ((unsigned)f2bf(acc[i][j][1]) << 16);
        pk.y = (unsigned)f2bf(acc[i][j][2]) | ((unsigned)f2bf(acc[i][j][3]) << 16);
        *(uint2*)(T + nw * 36 + hm * 4) = pk;       // ds_write_b64
      }
    asm volatile("s_waitcnt lgkmcnt(0)" ::: "memory");  // wave-private: no barrier
    int h = nblk;                                   // BN=64: one head per block
    int d = lane;
    int b = m0 >> 11;
    int lbase = (m0 & (L_ - 1)) + wave * 32;
    unsigned short* C = pa.C[2];
    size_t rowbase = (((size_t)b * H_ + h) * DH_ + d) * L_ + lbase;
    #pragma unroll
    for (int t = 0; t < 4; ++t) {
      uint2 lo = *(uint2*)(T + lane * 36 + t * 8);
      uint2 hi = *(uint2*)(T + lane * 36 + t * 8 + 4);
      uint4 o = {lo.x, lo.y, hi.x, hi.y};           // m-local [8t, 8t+8)
      *(uint4*)(C + rowbase + t * 8) = o;
    }
  }
}

// Output GEMM: fp32 row-major epilogue straight to d_out.
// Flat grid of 512; XCD-aware decode: each XCD gets 4 m-groups x 16 n.
__global__ __launch_bounds__(256) void gemm_out_kernel(
    const unsigned short* __restrict__ A, const unsigned short* __restrict__ Bt,
    float* __restrict__ C) {
  __shared__ unsigned short SH[24576];
  unsigned short* As = SH;
  unsigned short* Bs = SH + 16384;

  const int bflat = blockIdx.x;
  const int xcd = bflat & 7, s = bflat >> 3;      // s: 0..63
  const int nblk = s & 15;
  const int mblk = xcd * 4 + (s >> 4);            // 0..31
  const int m0 = mblk * BM, n0 = nblk * BN;

  f32x4 acc[2][4] = {};
  gemm_core_1024(A, Bt, As, Bs, acc, m0, n0);

  const int lane = threadIdx.x & 63, wave = threadIdx.x >> 6;
  const int quad = lane >> 4, l16 = lane & 15;
  #pragma unroll
  for (int i = 0; i < 2; ++i)
    #pragma unroll
    for (int j = 0; j < 4; ++j)
      #pragma unroll
      for (int r = 0; r < 4; ++r) {
        int m = m0 + wave * 32 + i * 16 + quad * 4 + r;
        int n = n0 + j * 16 + l16;
        C[(size_t)m * DIM_ + n] = acc[i][j][r];
      }
}

// ---------------------------------------------------------------- attention
// One block per (64-query tile, bh). Window = [q0-256, q0+63] -> 320 keys = 20 chunks.
// R6: (1) K staging via global_load_lds w16 + XOR swizzle (stride-64 rows; OOB
// keys clamped to 0, masked pre-exp). (2) PV phase writes ALL 10 P chunks per
// half, one barrier, then 5 uninterrupted frag+MFMA groups (was 10 lgkmcnt(0)
// serialization points). V keeps the explicit-zero register path (P=0 x garbage
// would be NaN).
#define NCH 20
__global__ __launch_bounds__(256) void attn_kernel(
    const unsigned short* __restrict__ Qh,  // (B,H,L,DH) roped
    const unsigned short* __restrict__ Kh,  // (B,H,L,DH) roped
    const unsigned short* __restrict__ Vt,  // (B,H,DH,L)
    unsigned short* __restrict__ O) {       // (B,L,H*DH) bf16
  __shared__ unsigned short KVs[64 * 168];  // K half: 160x64 = 20480 B; V half: 64x168 = 21504 B
  __shared__ unsigned short Ps[4][16 * 172]; // per-wave P (16 q x 160 k, stride 172)
  const int tid = threadIdx.x;
  const int wave = tid >> 6, lane = tid & 63;
  const int quad = lane >> 4, l16 = lane & 15;

  const int bflat = blockIdx.x;
  const int xcd = bflat & 7, s = bflat >> 3;  // s: 0..127
  const int qt = s >> 2;                      // 0..31 q-tile
  const int bh = xcd * 4 + (s & 3);           // 0..31

  const int q0 = qt * 64;
  const int kwin0 = q0 - WWIN;
  const int qb = q0 + wave * 16;

  // Q fragments held in registers: A[m=lane&15][k=quad*8+j], k0 in {0,32}
  bf16x8 qf0, qf1;
  {
    const unsigned short* qrow = Qh + ((size_t)bh * L_ + qb + l16) * DH_;
    qf0 = *(const bf16x8*)(qrow + quad * 8);
    qf1 = *(const bf16x8*)(qrow + 32 + quad * 8);
  }

  f32x4 S[NCH] = {};

  // ---- S = Q K^T over two K halves (async K staging, XOR swizzle) ----
  const int srow = tid >> 3, sc = tid & 7;   // 32 rows/pass, 8 chunks/row
  #pragma unroll
  for (int half = 0; half < 2; ++half) {
    __syncthreads();
    #pragma unroll
    for (int rep = 0; rep < 5; ++rep) {       // 160 rows x 8 chunks, 16B each
      int row = rep * 32 + srow;
      int key = kwin0 + half * 160 + row;
      key = key < 0 ? 0 : key;                // clamp: bogus-but-finite, masked pre-exp
      int cs = sc ^ (row & 7);
      gld_lds16(Kh + ((size_t)bh * L_ + key) * DH_ + cs * 8,
                (unsigned short*)KVs + row * 64 + sc * 8);
    }
    __syncthreads();                          // drains vmcnt
    #pragma unroll
    for (int cc = 0; cc < 10; ++cc) {
      int row = cc * 16 + l16;
      const unsigned short* kr = (const unsigned short*)KVs + row * 64;
      bf16x8 kf0 = *(const bf16x8*)(kr + ((quad) ^ (row & 7)) * 8);
      bf16x8 kf1 = *(const bf16x8*)(kr + ((4 + quad) ^ (row & 7)) * 8);
      int c = half * 10 + cc;
      S[c] = __builtin_amdgcn_mfma_f32_16x16x32_bf16(qf0, kf0, S[c], 0, 0, 0);
      S[c] = __builtin_amdgcn_mfma_f32_16x16x32_bf16(qf1, kf1, S[c], 0, 0, 0);
    }
  }

  // ---- masked softmax in registers (rows live in one 16-lane quad) ----
  float inv_l[4];
  #pragma unroll
  for (int r = 0; r < 4; ++r) {
    int i = qb + quad * 4 + r;
    float mx = -1e30f;
    #pragma unroll
    for (int c = 0; c < NCH; ++c) {
      int key = kwin0 + c * 16 + l16;
      bool valid = (key >= 0) && (key <= i) && (key >= i - WWIN);
      float v = valid ? S[c][r] * 0.125f : -1e30f;  // DH^-0.5 = 1/8; garbage masked out
      S[c][r] = v;
      mx = fmaxf(mx, v);
    }
    mx = fmaxf(mx, __shfl_xor(mx, 1));
    mx = fmaxf(mx, __shfl_xor(mx, 2));
    mx = fmaxf(mx, __shfl_xor(mx, 4));
    mx = fmaxf(mx, __shfl_xor(mx, 8));
    float sum = 0.f;
    #pragma unroll
    for (int c = 0; c < NCH; ++c) {
      float e = __expf(S[c][r] - mx);
      S[c][r] = e;
      sum += e;
    }
    sum += __shfl_xor(sum, 1);
    sum += __shfl_xor(sum, 2);
    sum += __shfl_xor(sum, 4);
    sum += __shfl_xor(sum, 8);
    inv_l[r] = 1.0f / sum;
  }

  // ---- O = P V over two V halves ----
  f32x4 Oacc[4] = {};
  unsigned short* pw = &Ps[wave][0];
  #pragma unroll
  for (int half = 0; half < 2; ++half) {
    __syncthreads();                          // protect V buffer from prior readers
    for (int rep = 0; rep < 5; ++rep) {       // stage V_t: 64 dh-rows x 20 chunks
      int ci = rep * 256 + tid;
      int row = ci / 20, c = ci % 20;
      int key0 = kwin0 + half * 160 + c * 8;
      uint4 val = {0, 0, 0, 0};
      if (key0 >= 0)
        val = *(const uint4*)(Vt + ((size_t)bh * DH_ + row) * L_ + key0);
      *(uint4*)(&KVs[row * 168 + c * 8]) = val;  // stride 168: ~2-way banks
    }
    // write ALL P chunks for this half (wave-private buffer, stride 172)
    #pragma unroll
    for (int cc = 0; cc < 10; ++cc)
      #pragma unroll
      for (int r = 0; r < 4; ++r) {
        float p = S[half * 10 + cc][r] * inv_l[r];
        pw[(quad * 4 + r) * 172 + cc * 16 + l16] = f2bf(p);  // C-layout -> [m][k]
      }
    __syncthreads();                          // V ready; P writes drained too
    #pragma unroll
    for (int s5 = 0; s5 < 5; ++s5) {
      bf16x8 pf = *(const bf16x8*)(pw + l16 * 172 + s5 * 32 + quad * 8);  // A-frag
      int lk = s5 * 32 + quad * 8;
      #pragma unroll
      for (int t = 0; t < 4; ++t) {
        bf16x8 vf = *(const bf16x8*)(&KVs[(t * 16 + l16) * 168 + lk]);
        Oacc[t] = __builtin_amdgcn_mfma_f32_16x16x32_bf16(pf, vf, Oacc[t], 0, 0, 0);
      }
    }
  }

  // epilogue: (B, L, H*DH) bf16
  int b = bh >> 4, h = bh & 15;
  #pragma unroll
  for (int t = 0; t < 4; ++t)
    #pragma unroll
    for (int r = 0; r < 4; ++r) {
      int l = qb + quad * 4 + r;
      int col = h * DH_ + t * 16 + l16;
      O[((size_t)b * L_ + l) * (H_ * DH_) + col] = f2bf(Oacc[t][r]);
    }
}

// ---------------------------------------------------------------- launch
extern "C" void kernel_launch(void* const* d_in, const int* in_sizes, int n_in,
                              void* d_out, int out_size, void* d_ws, size_t ws_size,
                              hipStream_t stream) {
  const float* q  = (const float*)d_in[0];
  const float* k  = (const float*)d_in[1];
  const float* v  = (const float*)d_in[2];
  const float* wq = (const float*)d_in[3];
  const float* wk = (const float*)d_in[4];
  const float* wv = (const float*)d_in[5];
  const float* wo = (const float*)d_in[6];

  const size_t SA = (size_t)B_ * L_ * DIM_;  // 4,194,304
  const size_t SW = (size_t)DIM_ * DIM_;     // 1,048,576
  unsigned short* w   = (unsigned short*)d_ws;
  unsigned short* qb  = w; w += SA;
  unsigned short* kb  = w; w += SA;
  unsigned short* vb  = w; w += SA;
  unsigned short* wqb = w; w += SW;
  unsigned short* wkb = w; w += SW;
  unsigned short* wvb = w; w += SW;
  unsigned short* wob = w; w += SW;
  unsigned short* qh  = w; w += SA;   // (B,H,L,DH) roped
  unsigned short* kh  = w; w += SA;   // (B,H,L,DH) roped
  unsigned short* vt  = w; w += SA;   // (B,H,DH,L)
  unsigned short* Ob  = w; w += SA;   // (B,L,H*DH)

  CastArgs ca;
  ca.src[0] = q;  ca.dst[0] = qb;  ca.n[0] = (int)SA;
  ca.src[1] = k;  ca.dst[1] = kb;  ca.n[1] = (int)SA;
  ca.src[2] = v;  ca.dst[2] = vb;  ca.n[2] = (int)SA;
  ca.src[3] = wq; ca.dst[3] = wqb; ca.n[3] = (int)SW;
  ca.src[4] = wk; ca.dst[4] = wkb; ca.n[4] = (int)SW;
  ca.src[5] = wv; ca.dst[5] = wvb; ca.n[5] = (int)SW;
  ca.src[6] = wo; ca.dst[6] = wob; ca.n[6] = (int)SW;
  cast_bf16_kernel<<<dim3(SA / (256 * 4), 7), 256, 0, stream>>>(ca);

  ProjArgs pa;
  pa.A[0] = qb; pa.Bt[0] = wqb; pa.C[0] = qh;
  pa.A[1] = kb; pa.Bt[1] = wkb; pa.C[1] = kh;
  pa.A[2] = vb; pa.Bt[2] = wvb; pa.C[2] = vt;
  gemm_proj_kernel<<<dim3(16 * 32 * 3), 256, 0, stream>>>(pa);

  attn_kernel<<<dim3(32 * 32), 256, 0, stream>>>(qh, kh, vt, Ob);
  gemm_out_kernel<<<dim3(16 * 32), 256, 0, stream>>>(Ob, wob, (float*)d_out);
}